// Round 1
// baseline (3704.990 us; speedup 1.0000x reference)
//
#include <hip/hip_runtime.h>
#include <cstdint>
#include <cstddef>

// ---------------------------------------------------------------------------
// GCN 2-layer forward. out[d] = dinv[d]*(g[d] + sum_{(s,d) in E} g[s]) + b,
// where g = dinv * (x @ W). Self-loop handled by initializing agg = g.
// ---------------------------------------------------------------------------

__global__ __launch_bounds__(256) void count_deg_k(const int* __restrict__ dst,
                                                   int* __restrict__ deg, int E) {
    int e = blockIdx.x * 256 + threadIdx.x;
    if (e < E) atomicAdd(&deg[dst[e]], 1);
}

__global__ __launch_bounds__(256) void dinv_k(const int* __restrict__ deg,
                                              float* __restrict__ dinv, int N) {
    int i = blockIdx.x * 256 + threadIdx.x;
    if (i < N) dinv[i] = rsqrtf((float)(deg[i] + 1));  // +1 = self loop
}

// X [N,128] @ W [128,OUT] -> row-scaled by dinv. Writes result to BOTH g and
// agg (agg init carries the self-loop term). 16 rows x OUT cols per block.
template <int OUT>
__global__ __launch_bounds__(256) void gemm_scale_k(
    const float* __restrict__ X, const float* __restrict__ W,
    const float* __restrict__ dinv,
    float* __restrict__ g, float* __restrict__ agg, int N) {
    constexpr int RPT = OUT / 16;  // rows per thread: 8 (OUT=128) / 4 (OUT=64)
    __shared__ float Ws[64 * OUT];     // K-chunk of W (64 x OUT)
    __shared__ float Xs[16 * 128];     // row tile of X

    const int t = threadIdx.x;
    const int row0 = blockIdx.x * 16;

    for (int i = t; i < 16 * 128; i += 256) {
        int r = i >> 7, k = i & 127;
        int gr = row0 + r;
        Xs[i] = (gr < N) ? X[(size_t)gr * 128 + k] : 0.0f;
    }

    const int c  = t % OUT;
    const int rg = t / OUT;

    float acc[RPT];
#pragma unroll
    for (int i = 0; i < RPT; ++i) acc[i] = 0.0f;

    for (int kc = 0; kc < 2; ++kc) {
        for (int i = t; i < 64 * OUT; i += 256) Ws[i] = W[kc * 64 * OUT + i];
        __syncthreads();
#pragma unroll 4
        for (int kk = 0; kk < 64; ++kk) {
            const int k = kc * 64 + kk;
            const float w = Ws[kk * OUT + c];
#pragma unroll
            for (int i = 0; i < RPT; ++i)
                acc[i] += Xs[(rg * RPT + i) * 128 + k] * w;
        }
        __syncthreads();
    }

#pragma unroll
    for (int i = 0; i < RPT; ++i) {
        int gr = row0 + rg * RPT + i;
        if (gr < N) {
            float v = acc[i] * dinv[gr];
            size_t off = (size_t)gr * OUT + c;
            g[off]   = v;
            agg[off] = v;
        }
    }
}

// One wave per edge: gather g[src] feature row, atomicAdd into agg[dst].
template <int F>
__global__ __launch_bounds__(256) void scatter_k(
    const float* __restrict__ g, float* __restrict__ agg,
    const int* __restrict__ src, const int* __restrict__ dst, int E) {
    const int wave = (blockIdx.x * 256 + threadIdx.x) >> 6;
    const int lane = threadIdx.x & 63;
    if (wave >= E) return;
    const int s = src[wave];
    const int d = dst[wave];
    if constexpr (F == 128) {
        const float2 v = ((const float2*)(g + (size_t)s * 128))[lane];
        float* a = agg + (size_t)d * 128 + lane * 2;
        atomicAdd(a, v.x);
        atomicAdd(a + 1, v.y);
    } else {
        const float v = g[(size_t)s * 64 + lane];
        atomicAdd(agg + (size_t)d * 64 + lane, v);
    }
}

// out = agg * dinv[row] + bias[col]   (works in-place: out may alias agg)
template <int F>
__global__ __launch_bounds__(256) void bias_scale_k(
    const float* __restrict__ agg, const float* __restrict__ bias,
    const float* __restrict__ dinv, float* __restrict__ out, int N) {
    const size_t i = (size_t)blockIdx.x * 256 + threadIdx.x;
    if (i < (size_t)N * F) {
        const int r = (int)(i / F);
        const int c = (int)(i % F);
        out[i] = agg[i] * dinv[r] + bias[c];
    }
}

extern "C" void kernel_launch(void* const* d_in, const int* in_sizes, int n_in,
                              void* d_out, int out_size, void* d_ws, size_t ws_size,
                              hipStream_t stream) {
    const float* x  = (const float*)d_in[0];
    const int*   ei = (const int*)d_in[1];
    const float* W1 = (const float*)d_in[2];
    const float* b1 = (const float*)d_in[3];
    const float* W2 = (const float*)d_in[4];
    const float* b2 = (const float*)d_in[5];
    float* out = (float*)d_out;

    const int N = in_sizes[0] / 128;   // 100000
    const int E = in_sizes[1] / 2;     // 3200000
    const int* src = ei;
    const int* dst = ei + E;

    // Workspace layout (ws re-poisoned every call; everything initialized here)
    char* ws = (char*)d_ws;
    const size_t NPAD = ((size_t)N * 4 + 255) & ~(size_t)255;
    int*   deg  = (int*)ws;
    float* dinv = (float*)(ws + NPAD);
    float* bufA = (float*)(ws + 2 * NPAD);                         // g1, then x2
    float* bufB = (float*)(ws + 2 * NPAD + (size_t)N * 128 * 4);   // agg1, then g2

    hipMemsetAsync(deg, 0, (size_t)N * 4, stream);
    count_deg_k<<<(E + 255) / 256, 256, 0, stream>>>(dst, deg, E);
    dinv_k<<<(N + 255) / 256, 256, 0, stream>>>(deg, dinv, N);

    // ---- layer 1: x [N,128] -> agg1 [N,128]
    gemm_scale_k<128><<<(N + 15) / 16, 256, 0, stream>>>(x, W1, dinv, bufA, bufB, N);
    scatter_k<128><<<(E + 3) / 4, 256, 0, stream>>>(bufA, bufB, src, dst, E);
    bias_scale_k<128><<<(int)(((size_t)N * 128 + 255) / 256), 256, 0, stream>>>(
        bufB, b1, dinv, bufA, N);

    // ---- layer 2: x2 [N,128] -> out [N,64]
    gemm_scale_k<64><<<(N + 15) / 16, 256, 0, stream>>>(bufA, W2, dinv, bufB, out, N);
    scatter_k<64><<<(E + 3) / 4, 256, 0, stream>>>(bufB, out, src, dst, E);
    bias_scale_k<64><<<(int)(((size_t)N * 64 + 255) / 256), 256, 0, stream>>>(
        out, b2, dinv, out, N);
}

// Round 2
// 1068.185 us; speedup vs baseline: 3.4685x; 3.4685x over previous
//
#include <hip/hip_runtime.h>
#include <cstdint>
#include <cstddef>

// ---------------------------------------------------------------------------
// GCN 2-layer forward, CSR-gather formulation (no float atomics).
//   g = dinv * (x @ W)
//   out[d] = dinv[d] * (g[d] + sum_{s in nbrs(d)} g[s]) + b
// CSR built per-call on device: deg count -> exclusive scan -> atomic fill.
// ---------------------------------------------------------------------------

__global__ __launch_bounds__(256) void count_deg_k(const int* __restrict__ dst,
                                                   int* __restrict__ deg, int E) {
    int e = blockIdx.x * 256 + threadIdx.x;
    if (e < E) atomicAdd(&deg[dst[e]], 1);
}

// per-1024-chunk sums for the scan
__global__ __launch_bounds__(256) void block_sum_k(const int* __restrict__ deg,
                                                   int* __restrict__ part, int N) {
    __shared__ int s[256];
    const int t = threadIdx.x;
    const int base = blockIdx.x * 1024 + t * 4;
    int v = 0;
#pragma unroll
    for (int i = 0; i < 4; ++i) { int idx = base + i; if (idx < N) v += deg[idx]; }
    s[t] = v; __syncthreads();
    for (int o = 128; o > 0; o >>= 1) { if (t < o) s[t] += s[t + o]; __syncthreads(); }
    if (t == 0) part[blockIdx.x] = s[0];
}

// exclusive scan of the (<=1024) chunk sums, single block
__global__ __launch_bounds__(256) void scan_part_k(int* __restrict__ part, int nb) {
    __shared__ int s[1024];
    const int t = threadIdx.x;
    for (int i = t; i < nb; i += 256) s[i] = part[i];
    __syncthreads();
    if (t == 0) { int acc = 0; for (int i = 0; i < nb; ++i) { int v = s[i]; s[i] = acc; acc += v; } }
    __syncthreads();
    for (int i = t; i < nb; i += 256) part[i] = s[i];
}

// exclusive scan within each 1024-chunk + chunk offset -> rowptr
__global__ __launch_bounds__(256) void scan_block_k(const int* __restrict__ deg,
                                                    const int* __restrict__ part,
                                                    int* __restrict__ rowptr, int N) {
    __shared__ int s[256];
    const int t = threadIdx.x;
    const int idx0 = blockIdx.x * 1024 + t * 4;
    int v[4]; int sum = 0;
#pragma unroll
    for (int i = 0; i < 4; ++i) { int idx = idx0 + i; v[i] = (idx < N) ? deg[idx] : 0; sum += v[i]; }
    s[t] = sum; __syncthreads();
    // inclusive Hillis-Steele over 256 thread-sums
    for (int o = 1; o < 256; o <<= 1) {
        int x = (t >= o) ? s[t - o] : 0;
        __syncthreads(); s[t] += x; __syncthreads();
    }
    int excl = ((t > 0) ? s[t - 1] : 0) + part[blockIdx.x];
#pragma unroll
    for (int i = 0; i < 4; ++i) { int idx = idx0 + i; if (idx < N) rowptr[idx] = excl; excl += v[i]; }
}

// dinv = rsqrt(deg+1); pos = rowptr (fill cursor); rowptr[N] = E
__global__ __launch_bounds__(256) void init_k(const int* __restrict__ deg,
                                              const int* __restrict__ rowptr,
                                              float* __restrict__ dinv,
                                              int* __restrict__ pos,
                                              int* __restrict__ rowptr_end,
                                              int N, int E) {
    int i = blockIdx.x * 256 + threadIdx.x;
    if (i < N) { dinv[i] = rsqrtf((float)(deg[i] + 1)); pos[i] = rowptr[i]; }
    if (i == 0) *rowptr_end = E;
}

__global__ __launch_bounds__(256) void fill_csr_k(const int* __restrict__ src,
                                                  const int* __restrict__ dst,
                                                  int* __restrict__ pos,
                                                  int* __restrict__ csr, int E) {
    int e = blockIdx.x * 256 + threadIdx.x;
    if (e < E) { int p = atomicAdd(&pos[dst[e]], 1); csr[p] = src[e]; }
}

// X [N,128] @ W [128,OUT], row-scaled by dinv -> g. 16 rows x OUT cols / block.
template <int OUT>
__global__ __launch_bounds__(256) void gemm_scale_k(
    const float* __restrict__ X, const float* __restrict__ W,
    const float* __restrict__ dinv, float* __restrict__ g, int N) {
    constexpr int RPT = OUT / 16;
    __shared__ float Ws[64 * OUT];
    __shared__ float Xs[16 * 128];

    const int t = threadIdx.x;
    const int row0 = blockIdx.x * 16;

    for (int i = t; i < 16 * 128; i += 256) {
        int r = i >> 7, k = i & 127;
        int gr = row0 + r;
        Xs[i] = (gr < N) ? X[(size_t)gr * 128 + k] : 0.0f;
    }

    const int c  = t % OUT;
    const int rg = t / OUT;

    float acc[RPT];
#pragma unroll
    for (int i = 0; i < RPT; ++i) acc[i] = 0.0f;

    for (int kc = 0; kc < 2; ++kc) {
        for (int i = t; i < 64 * OUT; i += 256) Ws[i] = W[kc * 64 * OUT + i];
        __syncthreads();
#pragma unroll 4
        for (int kk = 0; kk < 64; ++kk) {
            const int k = kc * 64 + kk;
            const float w = Ws[kk * OUT + c];
#pragma unroll
            for (int i = 0; i < RPT; ++i)
                acc[i] += Xs[(rg * RPT + i) * 128 + k] * w;
        }
        __syncthreads();
    }

#pragma unroll
    for (int i = 0; i < RPT; ++i) {
        int gr = row0 + rg * RPT + i;
        if (gr < N) g[(size_t)gr * OUT + c] = acc[i] * dinv[gr];
    }
}

// One wave per node: out[d] = dinv[d]*(g[d] + sum_nbr g[s]) + bias
template <int F>
__global__ __launch_bounds__(256) void agg_k(
    const float* __restrict__ g, const int* __restrict__ rowptr,
    const int* __restrict__ csr, const float* __restrict__ dinv,
    const float* __restrict__ bias, float* __restrict__ out, int N) {
    const int d = (blockIdx.x * 256 + threadIdx.x) >> 6;
    const int lane = threadIdx.x & 63;
    if (d >= N) return;
    const int beg = rowptr[d];
    const int end = rowptr[d + 1];

    if constexpr (F == 128) {
        float2 acc = ((const float2*)(g + (size_t)d * 128))[lane];
        int e = beg;
        if (e < end) {
            int s = csr[e];
            for (++e; e < end; ++e) {
                int s_next = csr[e];                       // prefetch next id
                float2 v = ((const float2*)(g + (size_t)s * 128))[lane];
                acc.x += v.x; acc.y += v.y;
                s = s_next;
            }
            float2 v = ((const float2*)(g + (size_t)s * 128))[lane];
            acc.x += v.x; acc.y += v.y;
        }
        const float di = dinv[d];
        float2 o; o.x = acc.x * di + bias[lane * 2]; o.y = acc.y * di + bias[lane * 2 + 1];
        ((float2*)(out + (size_t)d * 128))[lane] = o;
    } else {
        float acc = g[(size_t)d * 64 + lane];
        int e = beg;
        if (e < end) {
            int s = csr[e];
            for (++e; e < end; ++e) {
                int s_next = csr[e];
                acc += g[(size_t)s * 64 + lane];
                s = s_next;
            }
            acc += g[(size_t)s * 64 + lane];
        }
        out[(size_t)d * 64 + lane] = acc * dinv[d] + bias[lane];
    }
}

extern "C" void kernel_launch(void* const* d_in, const int* in_sizes, int n_in,
                              void* d_out, int out_size, void* d_ws, size_t ws_size,
                              hipStream_t stream) {
    const float* x  = (const float*)d_in[0];
    const int*   ei = (const int*)d_in[1];
    const float* W1 = (const float*)d_in[2];
    const float* b1 = (const float*)d_in[3];
    const float* W2 = (const float*)d_in[4];
    const float* b2 = (const float*)d_in[5];
    float* out = (float*)d_out;

    const int N = in_sizes[0] / 128;   // 100000
    const int E = in_sizes[1] / 2;     // 3200000
    const int* src = ei;
    const int* dst = ei + E;

    // ---- workspace carve-up (all buffers fully initialized each call)
    char* ws = (char*)d_ws;
    auto take = [&](size_t bytes) { char* p = ws; ws += (bytes + 255) & ~(size_t)255; return p; };
    int*   deg    = (int*)  take((size_t)N * 4);
    int*   rowptr = (int*)  take((size_t)(N + 1) * 4);
    int*   pos    = (int*)  take((size_t)N * 4);
    int*   part   = (int*)  take(1024 * 4);
    float* dinv   = (float*)take((size_t)N * 4);
    int*   csr    = (int*)  take((size_t)E * 4);
    float* bufA   = (float*)take((size_t)N * 128 * 4);  // g1, then g2
    float* bufB   = (float*)take((size_t)N * 128 * 4);  // x2

    const int nChunk = (N + 1023) / 1024;

    hipMemsetAsync(deg, 0, (size_t)N * 4, stream);
    count_deg_k<<<(E + 255) / 256, 256, 0, stream>>>(dst, deg, E);
    block_sum_k<<<nChunk, 256, 0, stream>>>(deg, part, N);
    scan_part_k<<<1, 256, 0, stream>>>(part, nChunk);
    scan_block_k<<<nChunk, 256, 0, stream>>>(deg, part, rowptr, N);
    init_k<<<(N + 255) / 256, 256, 0, stream>>>(deg, rowptr, dinv, pos, rowptr + N, N, E);
    fill_csr_k<<<(E + 255) / 256, 256, 0, stream>>>(src, dst, pos, csr, E);

    const int aggBlocks = (int)(((size_t)N * 64 + 255) / 256);

    // ---- layer 1: x [N,128] -> x2 [N,128]
    gemm_scale_k<128><<<(N + 15) / 16, 256, 0, stream>>>(x, W1, dinv, bufA, N);
    agg_k<128><<<aggBlocks, 256, 0, stream>>>(bufA, rowptr, csr, dinv, b1, bufB, N);

    // ---- layer 2: x2 [N,128] -> out [N,64]
    gemm_scale_k<64><<<(N + 15) / 16, 256, 0, stream>>>(bufB, W2, dinv, bufA, N);
    agg_k<64><<<aggBlocks, 256, 0, stream>>>(bufA, rowptr, csr, dinv, b2, out, N);
}